// Round 4
// baseline (212.482 us; speedup 1.0000x reference)
//
#include <hip/hip_runtime.h>

// Fused MS-SSIM + L1, single pass. B=128, H=W=384 fp32.
// Levels k=1,2,4,7, box conv, zero pad p=k/2 (even k -> 385x385 output).
// Round 11: BAND-packing (not col-packing). r10 post-mortem: col-packed f2
// left hwin/squares scalar (cross-component shuffles) -> only -6%. Here the
// f2 components are (band g, band g+4) at the SAME column: two fully
// independent pixels -> every op (squares, hwin, rings, ssim, masks) is
// elementwise f2 = true 2-for-1. bpermutes double to 24/step (12/px = r9's
// rate; DS measured ~18% of pipe, not binding).
//  - column layout = r9-validated: 1 col/lane, 7 tiles x 56 owned cols,
//    identical ownership masks.
//  - schedule = r9-validated: load(u+3) -> consume(u) -> stage(u+2),
//    3 stage buffers, 3-slot load ring, 6-phase unroll (all indices static).
//  - rings/running sums = r10-validated, f2 over bands now.
//  - per-component row guards: band pair (g, g+4); comp1 of g==3 (band 7)
//    has one extra k2 row (t=51) and k4 row (t=52) -> f2 mask select there.
//  - 64-thread blocks (1 wave): no LDS, no __syncthreads. grid (7,4,128)
//    = 3584 blocks = 14/CU.
// Loads: comp0 rows R0-3..R0+53 (guard u>=0 only, max 197<384); comp1 rows
// +192 (guard row<=383 only; band 7 reads rows 384-389 -> zeros = zero-pad).

#define W 384
#define H 384
#define NB 128
#define NTILES 7
#define NPAIRS 4
#define NBLK (NTILES * NPAIRS * NB)   // 3584 blocks

typedef __attribute__((ext_vector_type(2))) float f2;

__device__ __forceinline__ float bp(int addr, float v) {
    return __int_as_float(__builtin_amdgcn_ds_bpermute(addr, __float_as_int(v)));
}
__device__ __forceinline__ f2 f2s(float v) { f2 r; r.x = v; r.y = v; return r; }

// Band-packed SSIM from UNNORMALIZED P/M sums. c1k42 = 2*C1*k^4 etc.
__device__ __forceinline__ f2 ssim_pm2(f2 Vp, f2 Vm, f2 Vpp, f2 Vmm,
                                       float k2, float c1k42, float c2k42) {
    const f2 p2 = Vp * Vp;
    const f2 m2 = Vm * Vm;
    const f2 d  = p2 - m2;              // 4*Sx*Sy
    const f2 s  = p2 + m2;              // 2*(Sx^2+Sy^2)
    const f2 dq = Vpp - Vmm;            // 4*Sxy
    const f2 sq = Vpp + Vmm;            // 2*(Sxx+Syy)
    const f2 A1 = d + c1k42;
    const f2 B1 = s + c1k42;
    const f2 A2 = __builtin_elementwise_fma(f2s(k2), dq, -d) + c2k42;
    const f2 B2 = __builtin_elementwise_fma(f2s(k2), sq, -s) + c2k42;
    const f2 num = A1 * A2;
    const f2 den = B1 * B2;
    f2 r;
    r.x = num.x * __builtin_amdgcn_rcpf(den.x);
    r.y = num.y * __builtin_amdgcn_rcpf(den.y);
    return r;
}

__global__ __launch_bounds__(64, 2) void msssim_main(
    const float* __restrict__ X, const float* __restrict__ Y,
    const float* __restrict__ dr, float* __restrict__ part)
{
    const int lane = threadIdx.x;               // 0..63 (one wave per block)
    const int tile = blockIdx.x;                // 0..6
    const int g    = blockIdx.y;                // band pair (g, g+4)
    const int b    = blockIdx.z;

    const int c  = -3 + 56 * tile + lane;       // this lane's window-start col
    const int R0 = 48 * g;                      // comp0 band start; comp1 = R0+192

    const float drb = dr[b];
    const float C1 = (0.01f * drb) * (0.01f * drb);
    const float C2 = (0.03f * drb) * (0.03f * drb);
    const float tC1 = 2.f * C1;                           // k=1
    const float C1_2 = C1 * 32.f,    C2_2 = C2 * 32.f;    // 2*k^4, k=2
    const float C1_4 = C1 * 512.f,   C2_4 = C2 * 512.f;   // k=4
    const float C1_7 = C1 * 4802.f,  C2_7 = C2 * 4802.f;  // k=7

    // column ownership masks (r9-validated): output col j = c + k/2
    const float m1 = (lane >= 3 && lane <= 58 && c     <= 383) ? 1.f : 0.f;
    const float m2 = (lane >= 2 && lane <= 57 && c + 1 <= 384) ? 1.f : 0.f;
    const float m4 = (lane >= 1 && lane <= 56 && c + 2 <= 384) ? 1.f : 0.f;
    const float m7 = (             lane <= 55 && c + 3 <= 383) ? 1.f : 0.f;
    const f2 mk1 = f2s(m1);
    const f2 mk7 = f2s(m7);

    // row-guard highs: comp1 of g==3 (band 7) gets one extra k2/k4 row
    const int k2hi = (g == 3) ? 52 : 51;
    const int k4hi = (g == 3) ? 53 : 52;

    // own-column load setup (clamped offset + zero mask, row-invariant)
    const float mcol = (c >= 0 && c < W) ? 1.f : 0.f;
    const int   cc   = c < 0 ? 0 : (c > W - 1 ? W - 1 : c);

    // bpermute byte addresses, shifts d=1..6 (wrap excluded by col masks)
    int ad[6];
#pragma unroll
    for (int d = 1; d <= 6; ++d) ad[d - 1] = ((lane + d) & 63) << 2;

    const float* __restrict__ Xb = X + (size_t)b * (H * W);
    const float* __restrict__ Yb = Y + (size_t)b * (H * W);

    // vertical state per quantity q in {p,m,pp,mm}, band-packed f2
    f2 r2[4], r4[3][4], r7[6][4], v4s[4], v7s[4];
#pragma unroll
    for (int q = 0; q < 4; ++q) {
        r2[q] = f2s(0.f);
        r4[0][q] = r4[1][q] = r4[2][q] = f2s(0.f);
#pragma unroll
        for (int a = 0; a < 6; ++a) r7[a][q] = f2s(0.f);
        v4s[q] = f2s(0.f); v7s[q] = f2s(0.f);
    }

    f2 ss1v = f2s(0.f), ss2v = f2s(0.f), ss4v = f2s(0.f),
       ss7v = f2s(0.f), l1v  = f2s(0.f);

    const int u0 = R0 - 3;        // 54 steps: comp0 row u; comp1 row u+192

    // 3-slot load ring (row u0+j -> slot j%3), f2 = (comp0, comp1)
    f2 rx[3], ry[3];
    auto loadv = [&](int u, int slot) {
        float x0 = 0.f, y0 = 0.f, x1 = 0.f, y1 = 0.f;
        if (u >= 0) {                       // comp0: max row 197 < 384
            x0 = Xb[(size_t)u * W + cc];
            y0 = Yb[(size_t)u * W + cc];
        }
        const int r1 = u + 192;
        if (r1 < H) {                       // comp1: min row 189 >= 0
            x1 = Xb[(size_t)r1 * W + cc];
            y1 = Yb[(size_t)r1 * W + cc];
        }
        f2 vx; vx.x = x0; vx.y = x1;
        f2 vy; vy.x = y0; vy.y = y1;
        rx[slot] = vx; ry[slot] = vy;
    };

    // 3 stage buffers (row u0+j -> buf j%3): own p,m + 12 f2 raw bperms
    f2 sp[3], sm[3], SRp[3][6], SRm[3][6];
    auto stageRow = [&](int slot, int buf) {
        const f2 p = (rx[slot] + ry[slot]) * f2s(mcol);
        const f2 m = (rx[slot] - ry[slot]) * f2s(mcol);
        sp[buf] = p; sm[buf] = m;
#pragma unroll
        for (int d = 0; d < 6; ++d) {
            f2 tp; tp.x = bp(ad[d], p.x); tp.y = bp(ad[d], p.y);
            f2 tm; tm.x = bp(ad[d], m.x); tm.y = bp(ad[d], m.y);
            SRp[buf][d] = tp; SRm[buf][d] = tm;
        }
    };

    // prologue: rows u0..u0+2 loaded (slots 0,1,2); rows u0,u0+1 staged
    loadv(u0,     0);
    loadv(u0 + 1, 1);
    loadv(u0 + 2, 2);
    stageRow(0, 0);
    stageRow(1, 1);

    for (int s = 0; s < 54; s += 6) {
#pragma unroll
        for (int ph = 0; ph < 6; ++ph) {
            const int t = s + ph;            // step index 0..53
            const int u = u0 + t;            // comp0 compute row

            // 1. load row u+3 -> slot (t+3)%3 == ph%3 (row u's loads dead)
            loadv(u + 3, ph % 3);

            // 2. consume row u from buf ph%3 (staged 2 steps ago)
            const int cb = ph % 3;
            const f2 p0 = sp[cb], m0 = sm[cb];
            const f2 pp0 = p0 * p0, mm0 = m0 * m0;

            f2 W2[4], W4[4], W7[4];
            {
                // q=p
                const f2 e1 = SRp[cb][0], e2 = SRp[cb][1], e3 = SRp[cb][2];
                const f2 e4 = SRp[cb][3], e5 = SRp[cb][4], e6 = SRp[cb][5];
                // q=m
                const f2 f1 = SRm[cb][0], f2e = SRm[cb][1], f3 = SRm[cb][2];
                const f2 f4 = SRm[cb][3], f5 = SRm[cb][4], f6 = SRm[cb][5];
                // p tree
                W2[0] = p0 + e1;
                W4[0] = W2[0] + (e2 + e3);
                W7[0] = (W4[0] + (e4 + e5)) + e6;
                // m tree
                W2[1] = m0 + f1;
                W4[1] = W2[1] + (f2e + f3);
                W7[1] = (W4[1] + (f4 + f5)) + f6;
                // pp tree (squares post-shift: exact)
                const f2 s1 = e1 * e1, s2 = e2 * e2, s3 = e3 * e3;
                const f2 s4 = e4 * e4, s5 = e5 * e5, s6 = e6 * e6;
                W2[2] = pp0 + s1;
                W4[2] = W2[2] + (s2 + s3);
                W7[2] = (W4[2] + (s4 + s5)) + s6;
                // mm tree
                const f2 t1 = f1 * f1, t2 = f2e * f2e, t3 = f3 * f3;
                const f2 t4 = f4 * f4, t5 = f5 * f5, t6 = f6 * f6;
                W2[3] = mm0 + t1;
                W4[3] = W2[3] + (t2 + t3);
                W7[3] = (W4[3] + (t4 + t5)) + t6;
            }

            f2 V2[4], V4[4], V7[4];
#pragma unroll
            for (int q = 0; q < 4; ++q) {
                V2[q] = W2[q] + r2[q];  r2[q] = W2[q];
                const f2 a4v = W4[q] + v4s[q];
                V4[q] = a4v;  v4s[q] = a4v - r4[2][q];
                r4[2][q] = r4[1][q]; r4[1][q] = r4[0][q]; r4[0][q] = W4[q];
                const f2 a7v = W7[q] + v7s[q];
                V7[q] = a7v;  v7s[q] = a7v - r7[5][q];
                r7[5][q] = r7[4][q]; r7[4][q] = r7[3][q]; r7[3][q] = r7[2][q];
                r7[2][q] = r7[1][q]; r7[1][q] = r7[0][q]; r7[0][q] = W7[q];
            }

            // k=1 (closed form), rows t in [3,51) both comps
            if (t >= 3 && t < 51) {
                const f2 num = (pp0 - mm0) + tC1;
                const f2 den = (pp0 + mm0) + tC1;
                f2 s1v;
                s1v.x = num.x * __builtin_amdgcn_rcpf(den.x);
                s1v.y = num.y * __builtin_amdgcn_rcpf(den.y);
                ss1v = __builtin_elementwise_fma(s1v, mk1, ss1v);
            }
            // k=2, i=u: comp0 t<51; comp1 t<k2hi (band7 extra row t=51)
            if (t >= 3 && t < k2hi) {
                f2 msk; msk.x = (t < 51) ? m2 : 0.f; msk.y = m2;
                ss2v = __builtin_elementwise_fma(
                    ssim_pm2(V2[0], V2[1], V2[2], V2[3], 4.f, C1_2, C2_2),
                    msk, ss2v);
            }
            // k=4, i=u-1: comp0 t<52; comp1 t<k4hi (band7 extra row t=52)
            if (t >= 4 && t < k4hi) {
                f2 msk; msk.x = (t < 52) ? m4 : 0.f; msk.y = m4;
                ss4v = __builtin_elementwise_fma(
                    ssim_pm2(V4[0], V4[1], V4[2], V4[3], 16.f, C1_4, C2_4),
                    msk, ss4v);
            }
            // k=7, i=u-3, t in [6,54) both comps; plus L1 (|Sm|, 1/49 in reduce)
            if (t >= 6) {
                ss7v = __builtin_elementwise_fma(
                    ssim_pm2(V7[0], V7[1], V7[2], V7[3], 49.f, C1_7, C2_7),
                    mk7, ss7v);
                f2 av; av.x = fabsf(V7[1].x); av.y = fabsf(V7[1].y);
                l1v = __builtin_elementwise_fma(av, mk7, l1v);
            }

            // 3. stage row u+2: slot (t+2)%3 -> buf (t+2)%3
            stageRow((ph + 2) % 3, (ph + 2) % 3);
        }
    }

    // combine band pair, wave reduce, one store per block per quantity
    float ss1 = ss1v.x + ss1v.y;
    float ss2 = ss2v.x + ss2v.y;
    float ss4 = ss4v.x + ss4v.y;
    float ss7 = ss7v.x + ss7v.y;
    float l1  = l1v.x  + l1v.y;
#pragma unroll
    for (int d = 32; d > 0; d >>= 1) {
        ss1 += __shfl_down(ss1, d, 64);
        ss2 += __shfl_down(ss2, d, 64);
        ss4 += __shfl_down(ss4, d, 64);
        ss7 += __shfl_down(ss7, d, 64);
        l1  += __shfl_down(l1,  d, 64);
    }
    if (lane == 0) {
        const int bid = ((int)blockIdx.z * NPAIRS + (int)blockIdx.y) * NTILES
                        + (int)blockIdx.x;
        part[bid * 5 + 0] = ss1;
        part[bid * 5 + 1] = ss2;
        part[bid * 5 + 2] = ss4;
        part[bid * 5 + 3] = ss7;
        part[bid * 5 + 4] = l1;
    }
}

__global__ __launch_bounds__(256) void reduce_final(
    const float* __restrict__ part, float* __restrict__ out)
{
    const int lane = threadIdx.x & 63;
    const int wv   = threadIdx.x >> 6;
    double d[5] = {0, 0, 0, 0, 0};
    for (int i = threadIdx.x; i < NBLK; i += 256) {
#pragma unroll
        for (int q = 0; q < 5; ++q) d[q] += (double)part[i * 5 + q];
    }
#pragma unroll
    for (int s = 32; s > 0; s >>= 1) {
#pragma unroll
        for (int q = 0; q < 5; ++q) d[q] += __shfl_down(d[q], s, 64);
    }
    __shared__ double sd[4][5];
    if (lane == 0) {
#pragma unroll
        for (int q = 0; q < 5; ++q) sd[wv][q] = d[q];
    }
    __syncthreads();
    if (threadIdx.x == 0) {
        double a[5];
#pragma unroll
        for (int q = 0; q < 5; ++q)
            a[q] = sd[0][q] + sd[1][q] + sd[2][q] + sd[3][q];
        const double n384 = (double)NB * 384.0 * 384.0;
        const double n385 = (double)NB * 385.0 * 385.0;
        const double m  = (a[0] / n384) * (a[1] / n385) * (a[2] / n385) * (a[3] / n384);
        const double l1 = a[4] / 49.0 / n384;
        out[0] = (float)(0.84 * (1.0 - m) + 0.16 * l1);
    }
}

extern "C" void kernel_launch(void* const* d_in, const int* in_sizes, int n_in,
                              void* d_out, int out_size, void* d_ws, size_t ws_size,
                              hipStream_t stream) {
    const float* X  = (const float*)d_in[0];
    const float* Y  = (const float*)d_in[1];
    const float* dr = (const float*)d_in[2];
    float* out  = (float*)d_out;
    float* part = (float*)d_ws;   // NBLK*5 floats = 71.7 KB

    dim3 grid(NTILES, NPAIRS, NB);
    msssim_main<<<grid, 64, 0, stream>>>(X, Y, dr, part);
    reduce_final<<<1, 256, 0, stream>>>(part, out);
}

// Round 5
// 201.159 us; speedup vs baseline: 1.0563x; 1.0563x over previous
//
#include <hip/hip_runtime.h>

// Fused MS-SSIM + L1, single pass. B=128, H=W=384 fp32.
// Levels k=1,2,4,7, box conv, zero pad p=k/2 (even k -> 385x385 output).
// Round 12: kill the lgkmcnt over-wait. r11's 24 bpermutes/step forced a
// lgkmcnt(15) wait on JUST-issued ops every step (needed wait was 24 — 4-bit
// field maxes at 15) -> DS-latency serialized per step; plus 1-wave blocks
// gave only ~1.4-3.5 resident waves/SIMD. This round:
//  (a) LDS row-window instead of bpermute: stage = ONE ds_write_b128 of
//      {p.x,p.y,m.x,m.y}; consume = SEVEN ds_read_b128 of lanes (l+d)&63,
//      d=0..6 (wrap == bpermute semantics; wrapped lanes masked as always).
//      8 DS ops/step (was 24), 16B each. Stride-16B b128 reads are the
//      standard conflict-free pattern.
//  (b) Schedule: load(u+3) -> consume(u) -> read7(u+1) -> write(u+2).
//      Consume's needed reads have exactly ONE newer DS op (the write) ->
//      lgkmcnt(1), encodable; reads get a full step of slack. DS ops are
//      in-order within a wave -> write(r)->read(r) needs no barrier.
//  (c) 256-thread blocks (4 waves, one band-pair each), wave-PRIVATE LDS
//      regions -> no __syncthreads anywhere. Grid (7,1,128) = 896 blocks
//      (r9's empirically better block shape).
//  (d) Band-packed f2 arithmetic identical to r11 (absmax 0 expected).

#define W 384
#define H 384
#define NB 128
#define NTILES 7
#define NPAIRS 4
#define NBLK (NTILES * NPAIRS * NB)   // 3584 part entries

typedef __attribute__((ext_vector_type(2))) float f2;

__device__ __forceinline__ f2 f2s(float v) { f2 r; r.x = v; r.y = v; return r; }
__device__ __forceinline__ f2 mkf2(float a, float b) { f2 r; r.x = a; r.y = b; return r; }

// Band-packed SSIM from UNNORMALIZED P/M sums. c1k42 = 2*C1*k^4 etc.
__device__ __forceinline__ f2 ssim_pm2(f2 Vp, f2 Vm, f2 Vpp, f2 Vmm,
                                       float k2, float c1k42, float c2k42) {
    const f2 p2 = Vp * Vp;
    const f2 m2 = Vm * Vm;
    const f2 d  = p2 - m2;              // 4*Sx*Sy
    const f2 s  = p2 + m2;              // 2*(Sx^2+Sy^2)
    const f2 dq = Vpp - Vmm;            // 4*Sxy
    const f2 sq = Vpp + Vmm;            // 2*(Sxx+Syy)
    const f2 A1 = d + c1k42;
    const f2 B1 = s + c1k42;
    const f2 A2 = __builtin_elementwise_fma(f2s(k2), dq, -d) + c2k42;
    const f2 B2 = __builtin_elementwise_fma(f2s(k2), sq, -s) + c2k42;
    const f2 num = A1 * A2;
    const f2 den = B1 * B2;
    f2 r;
    r.x = num.x * __builtin_amdgcn_rcpf(den.x);
    r.y = num.y * __builtin_amdgcn_rcpf(den.y);
    return r;
}

__global__ __launch_bounds__(256) void msssim_main(
    const float* __restrict__ X, const float* __restrict__ Y,
    const float* __restrict__ dr, float* __restrict__ part)
{
    const int lane = threadIdx.x & 63;
    const int wv   = threadIdx.x >> 6;          // 0..3 = band pair g
    const int tile = blockIdx.x;                // 0..6
    const int g    = wv;                        // band pair (g, g+4)
    const int b    = blockIdx.z;

    const int c  = -3 + 56 * tile + lane;       // this lane's window-start col
    const int R0 = 48 * g;                      // comp0 band start; comp1 = +192

    const float drb = dr[b];
    const float C1 = (0.01f * drb) * (0.01f * drb);
    const float C2 = (0.03f * drb) * (0.03f * drb);
    const float tC1 = 2.f * C1;                           // k=1
    const float C1_2 = C1 * 32.f,    C2_2 = C2 * 32.f;    // 2*k^4, k=2
    const float C1_4 = C1 * 512.f,   C2_4 = C2 * 512.f;   // k=4
    const float C1_7 = C1 * 4802.f,  C2_7 = C2 * 4802.f;  // k=7

    // column ownership masks (validated r9/r11): output col j = c + k/2
    const float m1 = (lane >= 3 && lane <= 58 && c     <= 383) ? 1.f : 0.f;
    const float m2 = (lane >= 2 && lane <= 57 && c + 1 <= 384) ? 1.f : 0.f;
    const float m4 = (lane >= 1 && lane <= 56 && c + 2 <= 384) ? 1.f : 0.f;
    const float m7 = (             lane <= 55 && c + 3 <= 383) ? 1.f : 0.f;
    const f2 mk1 = f2s(m1);
    const f2 mk7 = f2s(m7);

    // row-guard highs: comp1 of g==3 (band 7) gets one extra k2/k4 row
    const int k2hi = (g == 3) ? 52 : 51;
    const int k4hi = (g == 3) ? 53 : 52;

    // own-column load setup (clamped offset + zero mask, row-invariant)
    const float mcol = (c >= 0 && c < W) ? 1.f : 0.f;
    const int   cc   = c < 0 ? 0 : (c > W - 1 ? W - 1 : c);

    // wave-private LDS: [wave][buf 0..2][lane] float4 {p0,p1,m0,m1}
    __shared__ float4 lds4[4][3][64];
    float4* Lw = &lds4[wv][0][0];               // index as [buf*64 + idx]

    // window read indices, wrap mod 64 (== bpermute semantics; wrapped
    // lanes' results are excluded by the ownership masks)
    int nidx[7];
#pragma unroll
    for (int d = 0; d < 7; ++d) nidx[d] = (lane + d) & 63;

    const float* __restrict__ Xb = X + (size_t)b * (H * W);
    const float* __restrict__ Yb = Y + (size_t)b * (H * W);

    // vertical state per quantity q in {p,m,pp,mm}, band-packed f2
    f2 r2[4], r4[3][4], r7[6][4], v4s[4], v7s[4];
#pragma unroll
    for (int q = 0; q < 4; ++q) {
        r2[q] = f2s(0.f);
        r4[0][q] = r4[1][q] = r4[2][q] = f2s(0.f);
#pragma unroll
        for (int a = 0; a < 6; ++a) r7[a][q] = f2s(0.f);
        v4s[q] = f2s(0.f); v7s[q] = f2s(0.f);
    }

    f2 ss1v = f2s(0.f), ss2v = f2s(0.f), ss4v = f2s(0.f),
       ss7v = f2s(0.f), l1v  = f2s(0.f);

    const int u0 = R0 - 3;        // 54 steps: comp0 row u; comp1 row u+192

    // 3-slot global load ring (row u0+j -> slot j%3), f2 = (comp0, comp1)
    f2 rx[3], ry[3];
    auto loadv = [&](int u, int slot) {
        float x0 = 0.f, y0 = 0.f, x1 = 0.f, y1 = 0.f;
        if (u >= 0) {                       // comp0: max row 197 < 384
            x0 = Xb[(size_t)u * W + cc];
            y0 = Yb[(size_t)u * W + cc];
        }
        const int r1 = u + 192;
        if (r1 < H) {                       // comp1: min row 189 >= 0
            x1 = Xb[(size_t)r1 * W + cc];
            y1 = Yb[(size_t)r1 * W + cc];
        }
        rx[slot] = mkf2(x0, x1);
        ry[slot] = mkf2(y0, y1);
    };

    // stage: compute p,m and write ONE b128 {p.x,p.y,m.x,m.y} to buf
    auto stageRow = [&](int slot, int buf) {
        const f2 p = (rx[slot] + ry[slot]) * f2s(mcol);
        const f2 m = (rx[slot] - ry[slot]) * f2s(mcol);
        float4 v; v.x = p.x; v.y = p.y; v.z = m.x; v.w = m.y;
        Lw[buf * 64 + lane] = v;
    };

    float4 R[7];                 // 7-lane window of the NEXT compute row
    auto read7 = [&](int buf) {
#pragma unroll
        for (int d = 0; d < 7; ++d) R[d] = Lw[buf * 64 + nidx[d]];
    };

    // prologue: rows u0..u0+2 loaded (slots 0,1,2); rows u0,u0+1 staged;
    // window of row u0 read into R.
    loadv(u0,     0);
    loadv(u0 + 1, 1);
    loadv(u0 + 2, 2);
    stageRow(0, 0);
    stageRow(1, 1);
    read7(0);

    for (int s = 0; s < 54; s += 6) {
#pragma unroll
        for (int ph = 0; ph < 6; ++ph) {
            const int t = s + ph;            // step index 0..53
            const int u = u0 + t;            // comp0 compute row

            // 1. load row u+3 -> slot (t+3)%3 == ph%3 (row u's loads dead)
            loadv(u + 3, ph % 3);

            // 2. consume row u from R (read last step; only the stage-write
            //    is newer -> lgkmcnt(1))
            f2 ep[7], em[7];
#pragma unroll
            for (int d = 0; d < 7; ++d) {
                ep[d] = mkf2(R[d].x, R[d].y);
                em[d] = mkf2(R[d].z, R[d].w);
            }
            const f2 p0 = ep[0], m0 = em[0];
            const f2 pp0 = p0 * p0, mm0 = m0 * m0;

            f2 W2[4], W4[4], W7[4];
            {
                // p tree
                W2[0] = p0 + ep[1];
                W4[0] = W2[0] + (ep[2] + ep[3]);
                W7[0] = (W4[0] + (ep[4] + ep[5])) + ep[6];
                // m tree
                W2[1] = m0 + em[1];
                W4[1] = W2[1] + (em[2] + em[3]);
                W7[1] = (W4[1] + (em[4] + em[5])) + em[6];
                // pp tree (squares post-shift: exact)
                const f2 s1 = ep[1] * ep[1], s2 = ep[2] * ep[2], s3 = ep[3] * ep[3];
                const f2 s4 = ep[4] * ep[4], s5 = ep[5] * ep[5], s6 = ep[6] * ep[6];
                W2[2] = pp0 + s1;
                W4[2] = W2[2] + (s2 + s3);
                W7[2] = (W4[2] + (s4 + s5)) + s6;
                // mm tree
                const f2 t1 = em[1] * em[1], t2 = em[2] * em[2], t3 = em[3] * em[3];
                const f2 t4 = em[4] * em[4], t5 = em[5] * em[5], t6 = em[6] * em[6];
                W2[3] = mm0 + t1;
                W4[3] = W2[3] + (t2 + t3);
                W7[3] = (W4[3] + (t4 + t5)) + t6;
            }

            f2 V2[4], V4[4], V7[4];
#pragma unroll
            for (int q = 0; q < 4; ++q) {
                V2[q] = W2[q] + r2[q];  r2[q] = W2[q];
                const f2 a4v = W4[q] + v4s[q];
                V4[q] = a4v;  v4s[q] = a4v - r4[2][q];
                r4[2][q] = r4[1][q]; r4[1][q] = r4[0][q]; r4[0][q] = W4[q];
                const f2 a7v = W7[q] + v7s[q];
                V7[q] = a7v;  v7s[q] = a7v - r7[5][q];
                r7[5][q] = r7[4][q]; r7[4][q] = r7[3][q]; r7[3][q] = r7[2][q];
                r7[2][q] = r7[1][q]; r7[1][q] = r7[0][q]; r7[0][q] = W7[q];
            }

            // k=1 (closed form), rows t in [3,51) both comps
            if (t >= 3 && t < 51) {
                const f2 num = (pp0 - mm0) + tC1;
                const f2 den = (pp0 + mm0) + tC1;
                f2 s1v;
                s1v.x = num.x * __builtin_amdgcn_rcpf(den.x);
                s1v.y = num.y * __builtin_amdgcn_rcpf(den.y);
                ss1v = __builtin_elementwise_fma(s1v, mk1, ss1v);
            }
            // k=2, i=u: comp0 t<51; comp1 t<k2hi (band7 extra row t=51)
            if (t >= 3 && t < k2hi) {
                f2 msk; msk.x = (t < 51) ? m2 : 0.f; msk.y = m2;
                ss2v = __builtin_elementwise_fma(
                    ssim_pm2(V2[0], V2[1], V2[2], V2[3], 4.f, C1_2, C2_2),
                    msk, ss2v);
            }
            // k=4, i=u-1: comp0 t<52; comp1 t<k4hi (band7 extra row t=52)
            if (t >= 4 && t < k4hi) {
                f2 msk; msk.x = (t < 52) ? m4 : 0.f; msk.y = m4;
                ss4v = __builtin_elementwise_fma(
                    ssim_pm2(V4[0], V4[1], V4[2], V4[3], 16.f, C1_4, C2_4),
                    msk, ss4v);
            }
            // k=7, i=u-3, t in [6,54) both comps; plus L1 (|Sm|, 1/49 in reduce)
            if (t >= 6) {
                ss7v = __builtin_elementwise_fma(
                    ssim_pm2(V7[0], V7[1], V7[2], V7[3], 49.f, C1_7, C2_7),
                    mk7, ss7v);
                f2 av; av.x = fabsf(V7[1].x); av.y = fabsf(V7[1].y);
                l1v = __builtin_elementwise_fma(av, mk7, l1v);
            }

            // 3. read window of row u+1 (buf (t+1)%3, written at iter t-1)
            read7((ph + 1) % 3);

            // 4. stage row u+2: slot (t+2)%3 -> buf (t+2)%3
            stageRow((ph + 2) % 3, (ph + 2) % 3);
        }
    }

    // combine band pair, wave reduce, one store per WAVE (no block reduce)
    float ss1 = ss1v.x + ss1v.y;
    float ss2 = ss2v.x + ss2v.y;
    float ss4 = ss4v.x + ss4v.y;
    float ss7 = ss7v.x + ss7v.y;
    float l1  = l1v.x  + l1v.y;
#pragma unroll
    for (int d = 32; d > 0; d >>= 1) {
        ss1 += __shfl_down(ss1, d, 64);
        ss2 += __shfl_down(ss2, d, 64);
        ss4 += __shfl_down(ss4, d, 64);
        ss7 += __shfl_down(ss7, d, 64);
        l1  += __shfl_down(l1,  d, 64);
    }
    if (lane == 0) {
        const int bid = ((int)blockIdx.z * NPAIRS + g) * NTILES + (int)blockIdx.x;
        part[bid * 5 + 0] = ss1;
        part[bid * 5 + 1] = ss2;
        part[bid * 5 + 2] = ss4;
        part[bid * 5 + 3] = ss7;
        part[bid * 5 + 4] = l1;
    }
}

__global__ __launch_bounds__(256) void reduce_final(
    const float* __restrict__ part, float* __restrict__ out)
{
    const int lane = threadIdx.x & 63;
    const int wv   = threadIdx.x >> 6;
    double d[5] = {0, 0, 0, 0, 0};
    for (int i = threadIdx.x; i < NBLK; i += 256) {
#pragma unroll
        for (int q = 0; q < 5; ++q) d[q] += (double)part[i * 5 + q];
    }
#pragma unroll
    for (int s = 32; s > 0; s >>= 1) {
#pragma unroll
        for (int q = 0; q < 5; ++q) d[q] += __shfl_down(d[q], s, 64);
    }
    __shared__ double sd[4][5];
    if (lane == 0) {
#pragma unroll
        for (int q = 0; q < 5; ++q) sd[wv][q] = d[q];
    }
    __syncthreads();
    if (threadIdx.x == 0) {
        double a[5];
#pragma unroll
        for (int q = 0; q < 5; ++q)
            a[q] = sd[0][q] + sd[1][q] + sd[2][q] + sd[3][q];
        const double n384 = (double)NB * 384.0 * 384.0;
        const double n385 = (double)NB * 385.0 * 385.0;
        const double m  = (a[0] / n384) * (a[1] / n385) * (a[2] / n385) * (a[3] / n384);
        const double l1 = a[4] / 49.0 / n384;
        out[0] = (float)(0.84 * (1.0 - m) + 0.16 * l1);
    }
}

extern "C" void kernel_launch(void* const* d_in, const int* in_sizes, int n_in,
                              void* d_out, int out_size, void* d_ws, size_t ws_size,
                              hipStream_t stream) {
    const float* X  = (const float*)d_in[0];
    const float* Y  = (const float*)d_in[1];
    const float* dr = (const float*)d_in[2];
    float* out  = (float*)d_out;
    float* part = (float*)d_ws;   // NBLK*5 floats = 71.7 KB

    dim3 grid(NTILES, 1, NB);
    msssim_main<<<grid, 256, 0, stream>>>(X, Y, dr, part);
    reduce_final<<<1, 256, 0, stream>>>(part, out);
}